// Round 7
// baseline (3925.285 us; speedup 1.0000x reference)
//
#include <hip/hip_runtime.h>

namespace {

constexpr int kT = 256;

typedef float f2 __attribute__((ext_vector_type(2)));
typedef float f4 __attribute__((ext_vector_type(4)));

__device__ __forceinline__ float fast_tanh(float x) {
    float e = __expf(2.0f * x);
    return 1.0f - 2.0f * __builtin_amdgcn_rcpf(e + 1.0f);
}

__device__ __forceinline__ float dpp_xor1(float x) {
    return __builtin_bit_cast(float, __builtin_amdgcn_update_dpp(
        0, __builtin_bit_cast(int, x), 0xB1, 0xF, 0xF, true)); // quad [1,0,3,2]
}
__device__ __forceinline__ float dpp_xor2(float x) {
    return __builtin_bit_cast(float, __builtin_amdgcn_update_dpp(
        0, __builtin_bit_cast(int, x), 0x4E, 0xF, 0xF, true)); // quad [2,3,0,1]
}
template <int PAT>
__device__ __forceinline__ float swz(float x) {
    return __builtin_bit_cast(float,
        __builtin_amdgcn_ds_swizzle(__builtin_bit_cast(int, x), PAT));
}

// activation rows padded to 132 floats (bank-shift 4 per row, 16B-aligned)
constexpr int kRS = 132;

__global__ __launch_bounds__(1024, 1) void hybrid_ode_kernel(
    const float* __restrict__ y0,
    const float* __restrict__ t_span,
    const float* __restrict__ meal,
    const float* __restrict__ tvns,
    const float* __restrict__ W_in, const float* __restrict__ b_in,
    const float* __restrict__ W_h,  const float* __restrict__ b_h,
    const float* __restrict__ W_out,const float* __restrict__ b_out,
    float* __restrict__ out)
{
    const int tid = threadIdx.x;
    const int w   = tid >> 6;           // wave 0..15
    const int l   = tid & 63;
    const int kc  = l & 31;             // k-chunk: k = 4kc..4kc+3
    const int jg  = (w << 1) | (l >> 5);// 0..31: j-group (4 cols)
    const int jb  = jg * 4;
    const int out16 = kc & 15;          // output owned after reduce-scatter
    const int r_p = out16 & 3;
    const int j_p = jb + (out16 >> 2);
    const int rw  = w & 3;              // row carried by waves 0..3
    const int row = blockIdx.x * 4 + rw;
    const bool pb0 = (kc & 1) != 0;
    const bool pb1 = (kc & 2) != 0;
    const bool pb2 = (kc & 4) != 0;
    const bool pb3 = (kc & 8) != 0;
    const bool wr_own = (kc & 16) == 0;

    __shared__ __align__(16) float hp0[4 * kRS];
    __shared__ __align__(16) float hp1[4 * kRS];
    __shared__ float win_s[9 * 128];
    __shared__ float bi_s[128];
    __shared__ float wo_s[128 * 6];
    __shared__ float bo_s[8];
    __shared__ float xb[4][12];         // [t, yc0..5, yc3, v]

    // ---- stage small weights to LDS (covered by first dyn barrier)
    for (int idx = tid; idx < 1152; idx += 1024) win_s[idx] = W_in[idx];
    if (tid < 128) bi_s[tid] = b_in[tid];
    if (tid < 768) wo_s[tid] = W_out[tid];
    if (tid < 6)   bo_s[tid] = b_out[tid];

    // ---- hidden weights: 48 VGPRs/thread, full residency
    f2 wgt[3][2][4];   // [layer][k-pair p][jj]: k = 4kc+2p (+1), col jb+jj
    #pragma unroll
    for (int ll = 0; ll < 3; ++ll)
        #pragma unroll
        for (int p = 0; p < 2; ++p)
            #pragma unroll
            for (int jj = 0; jj < 4; ++jj) {
                const float* s = W_h + (size_t)(ll * 128 + 4 * kc + 2 * p) * 128 + jb + jj;
                f2 v; v.x = s[0]; v.y = s[128];
                wgt[ll][p][jj] = v;
            }
    float bh[3];
    #pragma unroll
    for (int ll = 0; ll < 3; ++ll) bh[ll] = b_h[ll * 128 + j_p];

    // ---- RK4 state on waves 0..3 (lane-uniform)
    float y[6] = {0,0,0,0,0,0};
    if (w < 4) {
        #pragma unroll
        for (int s = 0; s < 6; ++s) y[s] = y0[row * 6 + s];
        if (l == 0) {
            #pragma unroll
            for (int s = 0; s < 6; ++s) out[(size_t)row * kT * 6 + s] = y[s];
        }
    }
    const float* mrow = meal + (size_t)row * kT;
    const float* vrow = tvns + (size_t)row * kT;

    // write features for next eval (waves 0..3, lane 0)
    auto wxb = [&](float t, const float* yc, float v) {
        if (w < 4 && l == 0) {
            xb[rw][0] = t;
            #pragma unroll
            for (int s = 0; s < 6; ++s) xb[rw][1 + s] = yc[s];
            xb[rw][7] = yc[3];
            xb[rw][8] = v;
        }
    };

    // one dyn eval: 5 barriers; p[] valid on waves 0..3 (includes b_out)
    auto dyn = [&](float* p) {
        __syncthreads();                          // xb (and staging) ready

        // input layer 9->128, waves 0..7: wave w -> row w>>1, 64 cols
        if (w < 8) {
            const int r = w >> 1;
            const int c = ((w & 1) << 6) | l;
            float s = bi_s[c];
            #pragma unroll
            for (int k = 0; k < 9; ++k) s += xb[r][k] * win_s[k * 128 + c];
            hp0[r * kRS + c] = fast_tanh(s);
        }
        __syncthreads();

        // 3 hidden layers 128->128, ping-pong
        #pragma unroll
        for (int ll = 0; ll < 3; ++ll) {
            const float* rb = (ll & 1) ? hp1 : hp0;
            float*       wb = (ll & 1) ? hp0 : hp1;

            f4 q0 = *(const f4*)(rb + 0 * kRS + 4 * kc);
            f4 q1 = *(const f4*)(rb + 1 * kRS + 4 * kc);
            f4 q2 = *(const f4*)(rb + 2 * kRS + 4 * kc);
            f4 q3 = *(const f4*)(rb + 3 * kRS + 4 * kc);
            f2 h[4][2];
            h[0][0] = __builtin_shufflevector(q0, q0, 0, 1);
            h[0][1] = __builtin_shufflevector(q0, q0, 2, 3);
            h[1][0] = __builtin_shufflevector(q1, q1, 0, 1);
            h[1][1] = __builtin_shufflevector(q1, q1, 2, 3);
            h[2][0] = __builtin_shufflevector(q2, q2, 0, 1);
            h[2][1] = __builtin_shufflevector(q2, q2, 2, 3);
            h[3][0] = __builtin_shufflevector(q3, q3, 0, 1);
            h[3][1] = __builtin_shufflevector(q3, q3, 2, 3);

            float A[16];   // A[(jj<<2)|r]
            #pragma unroll
            for (int jj = 0; jj < 4; ++jj)
                #pragma unroll
                for (int r = 0; r < 4; ++r) {
                    f2 a = h[r][0] * wgt[ll][0][jj];
                    a = h[r][1] * wgt[ll][1][jj] + a;
                    A[(jj << 2) | r] = a.x + a.y;
                }

            // 5-stage reduce-scatter over the 32-lane half; lane ends
            // with out = kc&15 summed over all 32 lanes.
            float B[8];
            #pragma unroll
            for (int i2 = 0; i2 < 8; ++i2) {
                float keep = pb0 ? A[2*i2+1] : A[2*i2];
                float give = pb0 ? A[2*i2]   : A[2*i2+1];
                B[i2] = keep + dpp_xor1(give);
            }
            float C[4];
            #pragma unroll
            for (int i2 = 0; i2 < 4; ++i2) {
                float keep = pb1 ? B[2*i2+1] : B[2*i2];
                float give = pb1 ? B[2*i2]   : B[2*i2+1];
                C[i2] = keep + dpp_xor2(give);
            }
            float D[2];
            #pragma unroll
            for (int i2 = 0; i2 < 2; ++i2) {
                float keep = pb2 ? C[2*i2+1] : C[2*i2];
                float give = pb2 ? C[2*i2]   : C[2*i2+1];
                D[i2] = keep + swz<0x101F>(give);   // xor4
            }
            {
                float keep = pb3 ? D[1] : D[0];
                float give = pb3 ? D[0] : D[1];
                float S = keep + swz<0x201F>(give); // xor8
                S += swz<0x401F>(S);                // xor16: merge dup halves
                if (wr_own)
                    wb[r_p * kRS + j_p] = fast_tanh(S + bh[ll]);
            }
            __syncthreads();
        }

        // output layer 128->6: waves 0..3 only (dedup); h lives in hp1
        if (w < 4) {
            float hA = hp1[rw * kRS + l];
            float hB = hp1[rw * kRS + 64 + l];
            #pragma unroll
            for (int s = 0; s < 6; ++s) {
                float ps = hA * wo_s[l * 6 + s] + hB * wo_s[(l + 64) * 6 + s];
                ps += dpp_xor1(ps);
                ps += dpp_xor2(ps);
                ps += swz<0x101F>(ps);
                ps += swz<0x201F>(ps);
                ps += swz<0x401F>(ps);
                ps += __shfl_xor(ps, 32);
                p[s] = ps + bo_s[s];
            }
        }
    };

    // ODE core: reads yc of THIS eval back from xb (saves live registers)
    auto ode = [&](float m, const float* p, float* d) {
        const float G = xb[rw][1], I = xb[rw][2], N = xb[rw][3];
        const float L = xb[rw][4], GE = xb[rw][5], F = xb[rw][6];
        d[0] = -0.01f*I*G + 0.05f*GE                                    + p[0];
        d[1] = (G/(100.0f+G))*(1.0f + 2.0f*L/(5.0f+L)) - 0.1f*I         + p[1];
        d[2] = -0.05f*N                                                 + p[2];
        d[3] = 0.05f*GE - 0.2f*L                                        + p[3];
        d[4] = m - 0.05f*GE                                             + p[4];
        d[5] = -0.01f*I*F                                               + p[5];
    };

    for (int i = 0; i < kT - 1; ++i) {
        float t0 = 0, t1 = 0, dt = 0, tm = 0;
        float m0 = 0, m1 = 0, mm = 0, v0 = 0, v1 = 0, vm = 0;
        if (w < 4) {
            t0 = t_span[i]; t1 = t_span[i + 1]; dt = t1 - t0; tm = t0 + 0.5f * dt;
            m0 = mrow[i]; m1 = mrow[i + 1]; mm = 0.5f * (m0 + m1);
            v0 = vrow[i]; v1 = vrow[i + 1]; vm = 0.5f * (v0 + v1);
        }
        float d[6], ksum[6], yc[6], p[6];

        wxb(t0, y, v0);
        dyn(p);
        if (w < 4) {
            ode(m0, p, d);
            #pragma unroll
            for (int s = 0; s < 6; ++s) { ksum[s] = d[s]; yc[s] = y[s] + 0.5f * dt * d[s]; }
        }
        wxb(tm, yc, vm);
        dyn(p);
        if (w < 4) {
            ode(mm, p, d);
            #pragma unroll
            for (int s = 0; s < 6; ++s) { ksum[s] += 2.0f * d[s]; yc[s] = y[s] + 0.5f * dt * d[s]; }
        }
        wxb(tm, yc, vm);
        dyn(p);
        if (w < 4) {
            ode(mm, p, d);
            #pragma unroll
            for (int s = 0; s < 6; ++s) { ksum[s] += 2.0f * d[s]; yc[s] = y[s] + dt * d[s]; }
        }
        wxb(t1, yc, v1);
        dyn(p);
        if (w < 4) {
            ode(m1, p, d);
            #pragma unroll
            for (int s = 0; s < 6; ++s) y[s] += (dt * (1.0f / 6.0f)) * (ksum[s] + d[s]);
            if (l == 0) {
                #pragma unroll
                for (int s = 0; s < 6; ++s)
                    out[((size_t)row * kT + (i + 1)) * 6 + s] = y[s];
            }
        }
    }
}

} // namespace

extern "C" void kernel_launch(void* const* d_in, const int* in_sizes, int n_in,
                              void* d_out, int out_size, void* d_ws, size_t ws_size,
                              hipStream_t stream) {
    const float* y0     = (const float*)d_in[0];
    const float* t_span = (const float*)d_in[1];
    const float* meal   = (const float*)d_in[2];
    const float* tvns   = (const float*)d_in[3];
    const float* W_in   = (const float*)d_in[4];
    const float* b_in   = (const float*)d_in[5];
    const float* W_h    = (const float*)d_in[6];
    const float* b_h    = (const float*)d_in[7];
    const float* W_out  = (const float*)d_in[8];
    const float* b_out  = (const float*)d_in[9];
    float* out          = (float*)d_out;

    hipLaunchKernelGGL(hybrid_ode_kernel, dim3(256), dim3(1024), 0, stream,
                       y0, t_span, meal, tvns,
                       W_in, b_in, W_h, b_h, W_out, b_out, out);
}